// Round 1
// baseline (665.276 us; speedup 1.0000x reference)
//
#include <hip/hip_runtime.h>
#include <hip/hip_bf16.h>

// ---------------------------------------------------------------------------
// Attention block, MI355X bf16-MFMA baseline (round 0).
// Shapes (hardcoded from setup_inputs): B=4 S=512 D=4096 H=32 HKV=8 HD=128
// START=512 T=1024, M=B*S=2048, NQKV=H*HD+2*HKV*HD=6144.
// ---------------------------------------------------------------------------

#define B_ 4
#define S_ 512
#define D_ 4096
#define H_ 32
#define HKV_ 8
#define HD_ 128
#define T_ 1024
#define M_ 2048
#define NQKV_ 6144

typedef __attribute__((ext_vector_type(8))) short bf16x8;  // 8 bf16 (4 VGPRs)
typedef __attribute__((ext_vector_type(4))) float f32x4;   // MFMA C/D

#define GLOAD_LDS16(g, l)                                                     \
  __builtin_amdgcn_global_load_lds(                                           \
      (const __attribute__((address_space(1))) void*)(g),                     \
      (__attribute__((address_space(3))) void*)(l), 16, 0, 0)

__device__ __forceinline__ void st_c(float* p, float v) { *p = v; }
__device__ __forceinline__ void st_c(__hip_bfloat16* p, float v) {
  *p = __float2bfloat16(v);
}
__device__ __forceinline__ float ld_f(const float* p) { return *p; }
__device__ __forceinline__ float ld_f(const __hip_bfloat16* p) {
  return __bfloat162float(*p);
}

// ---------------------------------------------------------------------------
// fp32 -> bf16 convert (vectorized float4 -> 4x bf16 packed 8B store)
// ---------------------------------------------------------------------------
__global__ void cvt_f32_bf16(const float* __restrict__ in,
                             __hip_bfloat16* __restrict__ out, long n) {
  long i = ((long)blockIdx.x * blockDim.x + threadIdx.x) * 4;
  if (i >= n) return;
  float4 v = *(const float4*)(in + i);
  __hip_bfloat16 t[4] = {__float2bfloat16(v.x), __float2bfloat16(v.y),
                         __float2bfloat16(v.z), __float2bfloat16(v.w)};
  *(uint2*)(out + i) = *(const uint2*)t;
}

// ---------------------------------------------------------------------------
// NT bf16 MFMA GEMM: C[m][n] = sum_k A[m][k]*B[n][k]; both operands K-contig.
// 128x128 tile, BK=32, 4 waves (2x2 of 64x64), mfma_f32_16x16x32_bf16.
// m97 structure: global_load_lds width=16, 2-barrier K loop.
// Batch: z -> (b = z/Hdiv, h = z%Hdiv); A += b*sAb + h*sAh;
//        B += b*sBb + (h/rep)*sBh; C += b*sCb + h*sCh.
// Requires M%128==0, N%128==0, K%32==0 (true for all uses here).
// ---------------------------------------------------------------------------
template <typename CT>
__global__ __launch_bounds__(256) void gemm_nt(
    const __hip_bfloat16* __restrict__ A, const __hip_bfloat16* __restrict__ B,
    CT* __restrict__ C, int M, int N, int K, long ldA, long ldB, long ldC,
    int Hdiv, int rep, long sAb, long sAh, long sBb, long sBh, long sCb,
    long sCh) {
  int z = blockIdx.z;
  int zb = z / Hdiv, zh = z - zb * Hdiv;
  A += (long)zb * sAb + (long)zh * sAh;
  B += (long)zb * sBb + (long)(zh / rep) * sBh;
  C += (long)zb * sCb + (long)zh * sCh;

  const int m0 = blockIdx.y * 128;
  const int n0 = blockIdx.x * 128;
  const int tid = threadIdx.x;
  const int wave = tid >> 6, lane = tid & 63;
  const int wm = (wave >> 1) * 64, wn = (wave & 1) * 64;
  const int lrow = lane & 15;      // fragment m/n index
  const int kq = (lane >> 4) * 8;  // fragment k offset (8 contiguous bf16)

  __shared__ __align__(16) __hip_bfloat16 As[128 * 32];
  __shared__ __align__(16) __hip_bfloat16 Bs[128 * 32];

  f32x4 acc[4][4];
#pragma unroll
  for (int i = 0; i < 4; i++)
#pragma unroll
    for (int j = 0; j < 4; j++) acc[i][j] = f32x4{0.f, 0.f, 0.f, 0.f};

  for (long kt = 0; kt < K; kt += 32) {
    // stage A,B tiles: 512 x 16B slots each; lane l of wave w handles
    // slot it*256 + w*64 + l; LDS dest = wave-uniform base + lane*16 (HW).
#pragma unroll
    for (int it = 0; it < 2; it++) {
      int slot = it * 256 + tid;
      int row = slot >> 2;            // 4 slots (64B = 32 bf16) per row
      int col = (slot & 3) * 8;       // bf16 elements
      const __hip_bfloat16* ga = A + (long)(m0 + row) * ldA + kt + col;
      const __hip_bfloat16* gb = B + (long)(n0 + row) * ldB + kt + col;
      int sbase = (it * 256 + wave * 64) * 8;  // wave-uniform, bf16 elems
      GLOAD_LDS16(ga, &As[sbase]);
      GLOAD_LDS16(gb, &Bs[sbase]);
    }
    __syncthreads();  // drains vmcnt: LDS tiles ready

    bf16x8 af[4], bfv[4];
#pragma unroll
    for (int i = 0; i < 4; i++) {
      af[i] = *(const bf16x8*)&As[(wm + i * 16 + lrow) * 32 + kq];
      bfv[i] = *(const bf16x8*)&Bs[(wn + i * 16 + lrow) * 32 + kq];
    }
#pragma unroll
    for (int i = 0; i < 4; i++)
#pragma unroll
      for (int j = 0; j < 4; j++)
        acc[i][j] =
            __builtin_amdgcn_mfma_f32_16x16x32_bf16(af[i], bfv[j], acc[i][j],
                                                    0, 0, 0);
    __syncthreads();  // all waves done reading before next stage overwrites
  }

  // epilogue: C/D map col = lane&15, row = (lane>>4)*4 + r  [measured m89/m91]
  const int crow0 = m0 + wm + (lane >> 4) * 4;
  const int ccol0 = n0 + wn + lrow;
#pragma unroll
  for (int i = 0; i < 4; i++)
#pragma unroll
    for (int j = 0; j < 4; j++)
#pragma unroll
      for (int r = 0; r < 4; r++)
        st_c(&C[(long)(crow0 + i * 16 + r) * ldC + (ccol0 + j * 16)],
             acc[i][j][r]);
}

// ---------------------------------------------------------------------------
// RoPE on Q and K-new (reads fp32 qkv, writes bf16 q (b,s,h,d) and bf16 K-new
// into assembled K (b,kvh,512+s,d)). Interleaved pairs (2i, 2i+1).
// grid (10, 2048) x 256: j in [0,2560): j<2048 -> Q pair, else K pair.
// ---------------------------------------------------------------------------
__global__ void rope_kernel(const float* __restrict__ qkv,
                            const float* __restrict__ fcos,
                            const float* __restrict__ fsin,
                            __hip_bfloat16* __restrict__ qb,
                            __hip_bfloat16* __restrict__ kb) {
  int m = blockIdx.y;                                  // 0..2047 (b*S+s)
  int j = blockIdx.x * blockDim.x + threadIdx.x;       // pair index
  if (j >= 2560) return;
  int s = m & (S_ - 1);
  long rowbase = (long)m * NQKV_;
  if (j < 2048) {  // Q: element pair (2j, 2j+1) in [0,4096)
    int dpair = j & 63;
    float a = qkv[rowbase + 2 * j], bb = qkv[rowbase + 2 * j + 1];
    float c = fcos[s * 64 + dpair], si = fsin[s * 64 + dpair];
    long o = (long)m * 4096 + 2 * j;
    qb[o] = __float2bfloat16(a * c - bb * si);
    qb[o + 1] = __float2bfloat16(a * si + bb * c);
  } else {  // K: pair (4096+2j2, ...)
    int j2 = j - 2048;  // 0..511
    int kvh = j2 >> 6, dpair = j2 & 63;
    float a = qkv[rowbase + 4096 + 2 * j2], bb = qkv[rowbase + 4096 + 2 * j2 + 1];
    float c = fcos[s * 64 + dpair], si = fsin[s * 64 + dpair];
    int b = m >> 9;
    long o = (((long)(b * HKV_ + kvh)) * T_ + 512 + s) * HD_ + 2 * dpair;
    kb[o] = __float2bfloat16(a * c - bb * si);
    kb[o + 1] = __float2bfloat16(a * si + bb * c);
  }
}

// K cache part: kb[b][kvh][t][d] = bf16(cache_k[b][t][kvh][d]), t<512.
__global__ void kcache_cvt(const float* __restrict__ cache_k,
                           __hip_bfloat16* __restrict__ kb) {
  long i = (long)blockIdx.x * 256 + threadIdx.x;  // over 4*8*512*128
  if (i >= (long)B_ * HKV_ * 512 * HD_) return;
  int d = i & 127;
  int t = (i >> 7) & 511;
  int kvh = (i >> 16) & 7;
  int b = i >> 19;
  long o = (((long)(b * HKV_ + kvh)) * T_ + t) * HD_ + d;
  kb[o] = __float2bfloat16(
      cache_k[(((long)(b * 512 + t)) * HKV_ + kvh) * HD_ + d]);
}

// V assemble+transpose: vtb[b][kvh][d][t] <- cache_v (t<512) / qkv xv (t>=512).
// LDS 32x32 tile transpose for coalescing both sides. grid (32,4,32) x (32,8).
__global__ void v_transpose(const float* __restrict__ cache_v,
                            const float* __restrict__ qkv,
                            __hip_bfloat16* __restrict__ vtb) {
  __shared__ float tile[32][33];
  int t0 = blockIdx.x * 32, d0 = blockIdx.y * 32;
  int bk = blockIdx.z;
  int b = bk >> 3, kvh = bk & 7;
#pragma unroll
  for (int it = 0; it < 4; it++) {
    int t = t0 + threadIdx.y + it * 8;
    int d = d0 + threadIdx.x;
    float v;
    if (t < 512)
      v = cache_v[(((long)(b * 512 + t)) * HKV_ + kvh) * HD_ + d];
    else
      v = qkv[((long)(b * S_) + (t - 512)) * NQKV_ + 5120 + kvh * HD_ + d];
    tile[threadIdx.y + it * 8][threadIdx.x] = v;
  }
  __syncthreads();
#pragma unroll
  for (int it = 0; it < 4; it++) {
    int d = d0 + threadIdx.y + it * 8;
    int t = t0 + threadIdx.x;
    vtb[((long)bk * HD_ + d) * T_ + t] =
        __float2bfloat16(tile[threadIdx.x][threadIdx.y + it * 8]);
  }
}

// ---------------------------------------------------------------------------
// Masked softmax over score rows. One block (256 thr) per (z,q) row of T=1024.
// Valid length L = 513+q (causal, START=512). Writes bf16 P in-place over the
// score row (P row overlays the first 2KB of its own S row => race-free).
// ---------------------------------------------------------------------------
template <typename SDT>
__global__ void softmax_kernel(SDT* __restrict__ Sb,
                               __hip_bfloat16* __restrict__ Pb, long ldS,
                               long ldP) {
  int q = blockIdx.x, z = blockIdx.y;
  long srow = ((long)z * S_ + q) * ldS;
  long prow = ((long)z * S_ + q) * ldP;
  int tid = threadIdx.x;
  int L = 513 + q;
  const float scale = 0.08838834764831845f;  // 1/sqrt(128)

  float v[4];
  float m = -1e30f;
#pragma unroll
  for (int i = 0; i < 4; i++) {
    int k = tid + i * 256;
    float s = (k < L) ? ld_f(&Sb[srow + k]) * scale : -1e30f;
    v[i] = s;
    m = fmaxf(m, s);
  }
#pragma unroll
  for (int off = 32; off; off >>= 1) m = fmaxf(m, __shfl_xor(m, off));
  __shared__ float redm[4], reds[4];
  int wid = tid >> 6;
  if ((tid & 63) == 0) redm[wid] = m;
  __syncthreads();  // also: all S reads complete before in-place P writes
  m = fmaxf(fmaxf(redm[0], redm[1]), fmaxf(redm[2], redm[3]));

  float sum = 0.f, p[4];
#pragma unroll
  for (int i = 0; i < 4; i++) {
    int k = tid + i * 256;
    p[i] = (k < L) ? __expf(v[i] - m) : 0.f;
    sum += p[i];
  }
#pragma unroll
  for (int off = 32; off; off >>= 1) sum += __shfl_xor(sum, off);
  if ((tid & 63) == 0) reds[wid] = sum;
  __syncthreads();
  sum = reds[0] + reds[1] + reds[2] + reds[3];
  float inv = 1.f / sum;
#pragma unroll
  for (int i = 0; i < 4; i++) {
    int k = tid + i * 256;
    Pb[prow + k] = __float2bfloat16(p[i] * inv);
  }
}

// ---------------------------------------------------------------------------
extern "C" void kernel_launch(void* const* d_in, const int* in_sizes, int n_in,
                              void* d_out, int out_size, void* d_ws,
                              size_t ws_size, hipStream_t stream) {
  const float* x = (const float*)d_in[0];
  const float* wq = (const float*)d_in[1];
  const float* wk = (const float*)d_in[2];
  const float* wv = (const float*)d_in[3];
  const float* wo = (const float*)d_in[4];
  const float* fcos = (const float*)d_in[5];
  const float* fsin = (const float*)d_in[6];
  const float* cache_k = (const float*)d_in[7];
  const float* cache_v = (const float*)d_in[8];
  float* out = (float*)d_out;

  // ---- workspace layout (phase-aliased; stream order guarantees safety) ----
  // R0: xb (QKV-GEMM A) -> qb (rope'd Q) -> ob (attn out), all 16.8MB bf16
  // R1: wqkv bf16 (50.3MB) -> wo bf16 (33.6MB)
  // R2: qkv fp32 (50.3MB) -> scores S (268.4MB fp32 or 134.2MB bf16; P bf16
  //     packed in-place over S rows)
  // R3: kb  bf16 (b,kvh,t,d)   8.4MB
  // R4: vtb bf16 (b,kvh,d,t)   8.4MB
  char* ws = (char*)d_ws;
  const size_t szR0 = (size_t)M_ * 4096 * 2;
  const size_t szR1 = (size_t)NQKV_ * D_ * 2;
  const size_t szS_f32 = (size_t)B_ * H_ * S_ * T_ * 4;
  const size_t szKV = (size_t)B_ * HKV_ * T_ * HD_ * 2;
  const size_t base = szR0 + szR1 + 2 * szKV;
  bool sf32 = (ws_size >= base + szS_f32 + 1024);
  const size_t szR2 = sf32 ? szS_f32 : szS_f32 / 2;

  size_t R0 = 0;
  size_t R1 = R0 + szR0;
  size_t R2 = R1 + szR1;
  size_t R3 = R2 + szR2;
  size_t R4 = R3 + szKV;

  __hip_bfloat16* xb = (__hip_bfloat16*)(ws + R0);   // also qb, ob
  __hip_bfloat16* wqkvb = (__hip_bfloat16*)(ws + R1);  // also wob
  float* qkvf = (float*)(ws + R2);
  __hip_bfloat16* kb = (__hip_bfloat16*)(ws + R3);
  __hip_bfloat16* vtb = (__hip_bfloat16*)(ws + R4);

  dim3 blk(256);

  // 1) converts: x, wq|wk|wv -> bf16
  cvt_f32_bf16<<<(M_ * (long)D_ / 4 + 255) / 256, blk, 0, stream>>>(
      x, xb, (long)M_ * D_);
  cvt_f32_bf16<<<((long)D_ * D_ / 4 + 255) / 256, blk, 0, stream>>>(
      wq, wqkvb, (long)D_ * D_);
  cvt_f32_bf16<<<((long)1024 * D_ / 4 + 255) / 256, blk, 0, stream>>>(
      wk, wqkvb + (long)4096 * D_, (long)1024 * D_);
  cvt_f32_bf16<<<((long)1024 * D_ / 4 + 255) / 256, blk, 0, stream>>>(
      wv, wqkvb + (long)5120 * D_, (long)1024 * D_);

  // 2) QKV projection: qkvf[m][e] = sum_d xb[m][d] * wqkv[e][d]
  gemm_nt<float><<<dim3(NQKV_ / 128, M_ / 128, 1), blk, 0, stream>>>(
      xb, wqkvb, qkvf, M_, NQKV_, D_, D_, D_, NQKV_, 1, 1, 0, 0, 0, 0, 0, 0);

  // 3) RoPE -> qb (reuses R0; xb dead), K-new into kb
  __hip_bfloat16* qb = xb;
  rope_kernel<<<dim3(10, M_), blk, 0, stream>>>(qkvf, fcos, fsin, qb, kb);

  // 4) K cache convert, V assemble+transpose
  kcache_cvt<<<((long)B_ * HKV_ * 512 * HD_ + 255) / 256, blk, 0, stream>>>(
      cache_k, kb);
  v_transpose<<<dim3(T_ / 32, HD_ / 32, B_ * HKV_), dim3(32, 8), 0, stream>>>(
      cache_v, qkvf, vtb);

  // 5) wo -> bf16 (R1; wqkv dead after step 2, stream-ordered)
  __hip_bfloat16* wob = wqkvb;
  cvt_f32_bf16<<<((long)D_ * D_ / 4 + 255) / 256, blk, 0, stream>>>(
      wo, wob, (long)D_ * D_);

  // 6) scores: S[z][q][k] = sum_d Q[b,q,h,d] * K[b,kvh,k,d]; z=b*H+h
  long ldP = sf32 ? 2 * T_ : T_;
  if (sf32) {
    gemm_nt<float><<<dim3(T_ / 128, S_ / 128, B_ * H_), blk, 0, stream>>>(
        qb, kb, (float*)(ws + R2), S_, T_, HD_, (long)H_ * HD_, HD_, T_, H_, 4,
        (long)S_ * H_ * HD_, HD_, (long)HKV_ * T_ * HD_, (long)T_ * HD_,
        (long)H_ * S_ * T_, (long)S_ * T_);
    softmax_kernel<float><<<dim3(S_, B_ * H_), blk, 0, stream>>>(
        (float*)(ws + R2), (__hip_bfloat16*)(ws + R2), T_, ldP);
  } else {
    gemm_nt<__hip_bfloat16>
        <<<dim3(T_ / 128, S_ / 128, B_ * H_), blk, 0, stream>>>(
            qb, kb, (__hip_bfloat16*)(ws + R2), S_, T_, HD_, (long)H_ * HD_,
            HD_, T_, H_, 4, (long)S_ * H_ * HD_, HD_, (long)HKV_ * T_ * HD_,
            (long)T_ * HD_, (long)H_ * S_ * T_, (long)S_ * T_);
    softmax_kernel<__hip_bfloat16><<<dim3(S_, B_ * H_), blk, 0, stream>>>(
        (__hip_bfloat16*)(ws + R2), (__hip_bfloat16*)(ws + R2), T_, ldP);
  }

  // 7) PV: ob[b,q,h,d] = sum_k P[z][q][k] * VT[b,kvh,d,k]  (R0; qb dead)
  __hip_bfloat16* ob = xb;
  gemm_nt<__hip_bfloat16><<<dim3(HD_ / 128, S_ / 128, B_ * H_), blk, 0,
                            stream>>>(
      (const __hip_bfloat16*)(ws + R2), vtb, ob, S_, HD_, T_, ldP, T_,
      (long)H_ * HD_, H_, 4, (long)H_ * S_ * ldP, (long)S_ * ldP,
      (long)HKV_ * HD_ * T_, (long)HD_ * T_, (long)S_ * H_ * HD_, (long)HD_);

  // 8) output projection: out[m][d] = sum_e ob[m][e] * wo[d][e]
  gemm_nt<float><<<dim3(D_ / 128, M_ / 128, 1), blk, 0, stream>>>(
      ob, wob, out, M_, D_, D_, D_, D_, D_, 1, 1, 0, 0, 0, 0, 0, 0);
}